// Round 9
// baseline (147.277 us; speedup 1.0000x reference)
//
#include <hip/hip_runtime.h>
#include <stdint.h>

typedef unsigned short u16;
typedef unsigned int u32;
typedef __attribute__((ext_vector_type(8))) short short8;
typedef __attribute__((ext_vector_type(4))) float f32x4;
typedef __attribute__((ext_vector_type(16))) float f32x16;
typedef __attribute__((ext_vector_type(4))) u32 u32x4;

#define BATCH 16
#define CCH   512
#define NPIX  1024
#define NGRP  8
#define CPG   64
#define NHEAD 4
#define HDIM  128

__device__ __forceinline__ u16 f2bf(float f) {
  union { float f; u32 u; } v; v.f = f;
  u32 u = v.u;
  u32 r = (u + 0x7FFFu + ((u >> 16) & 1u)) >> 16;
  return (u16)r;
}
__device__ __forceinline__ float bf2f_lo(u32 w) {
  union { u32 u; float f; } v; v.u = w << 16; return v.f;
}
__device__ __forceinline__ float bf2f_hi(u32 w) {
  union { u32 u; float f; } v; v.u = w & 0xFFFF0000u; return v.f;
}

// async global->LDS, 16B per lane; dest = wave-uniform base + lane*16
__device__ __forceinline__ void gload16(const void* g, void* l) {
  typedef __attribute__((address_space(3))) u32 L;
  typedef __attribute__((address_space(1))) const u32 G;
  __builtin_amdgcn_global_load_lds((G*)(uintptr_t)g, (L*)(u32)(uintptr_t)l, 16, 0, 0);
}

#define CVTPK(dst, a, b) asm("v_cvt_pk_bf16_f32 %0, %1, %2" : "=v"(dst) : "v"(a), "v"(b))
#define PLSWAP(a, b) asm("v_permlane32_swap_b32 %0, %1" : "+v"(a), "+v"(b))

// 512B-pitch swizzled LDS fragment read (rows packed 4-per-512B, 4-bit XOR)
__device__ __forceinline__ short8 rd512(const char* base, int r, int ck, int hi) {
  int byte = ((r >> 2) * 512) +
             ((((r & 3) * 128) + ck * 32 + hi * 16) ^ (((r >> 2) & 15) << 4));
  return *reinterpret_cast<const short8*>(base + byte);
}

// softmax pack (32-kv tile): sn (16 scores, log2-domain) -> 2 P-fragments; returns lane-local psum
__device__ __forceinline__ float softmax_pack32(const f32x16& sn, short8* pf) {
  float ps = 0.f;
  u32 pw[8];
  #pragma unroll
  for (int u = 0; u < 8; ++u) {
    float pa = exp2f(sn[2*u]);
    float pb = exp2f(sn[2*u+1]);
    ps += pa + pb;
    CVTPK(pw[u], pa, pb);
  }
  PLSWAP(pw[0], pw[2]); PLSWAP(pw[1], pw[3]);
  PLSWAP(pw[4], pw[6]); PLSWAP(pw[5], pw[7]);
  u32x4 t0 = {pw[0], pw[1], pw[2], pw[3]};
  u32x4 t1 = {pw[4], pw[5], pw[6], pw[7]};
  pf[0] = __builtin_bit_cast(short8, t0);
  pf[1] = __builtin_bit_cast(short8, t1);
  return ps;
}

// ---------------- GroupNorm partial stats ----------------
__global__ void gn_stats_k(const float* __restrict__ x, float* __restrict__ part) {
  int bg = blockIdx.x >> 3, sl = blockIdx.x & 7;
  const float* p = x + (size_t)bg * (CPG * NPIX) + sl * 8192;
  float s = 0.f, ss = 0.f;
  for (int i = threadIdx.x; i < 2048; i += 256) {
    float4 v = reinterpret_cast<const float4*>(p)[i];
    s  += v.x + v.y + v.z + v.w;
    ss += v.x*v.x + v.y*v.y + v.z*v.z + v.w*v.w;
  }
  for (int o = 32; o > 0; o >>= 1) { s += __shfl_down(s, o); ss += __shfl_down(ss, o); }
  __shared__ float sh[8];
  int wid = threadIdx.x >> 6;
  if ((threadIdx.x & 63) == 0) { sh[wid*2] = s; sh[wid*2+1] = ss; }
  __syncthreads();
  if (threadIdx.x == 0) {
    part[blockIdx.x*2]   = sh[0]+sh[2]+sh[4]+sh[6];
    part[blockIdx.x*2+1] = sh[1]+sh[3]+sh[5]+sh[7];
  }
}

// ---------------- GroupNorm apply + transpose -> token-major bf16 xnT[tok][512] ----------------
__global__ __launch_bounds__(256) void gn_apply_t(const float* __restrict__ x,
                                                  const float* __restrict__ gamma,
                                                  const float* __restrict__ beta,
                                                  const float* __restrict__ part,
                                                  u16* __restrict__ xnT) {
  const int p0 = blockIdx.x * 64;
  const int c0 = blockIdx.y * 64;
  const int b  = blockIdx.z;
  __shared__ float lt[64][66];

  const int bg = b * NGRP + (c0 >> 6);
  float s = 0.f, ss = 0.f;
  #pragma unroll
  for (int k2 = 0; k2 < 8; ++k2) { s += part[(bg*8 + k2)*2]; ss += part[(bg*8 + k2)*2 + 1]; }
  const float invn = 1.f / (float)(CPG * NPIX);
  const float mean = s * invn;
  const float rstd = rsqrtf(ss * invn - mean * mean + 1e-5f);

  const int t = threadIdx.x;
  #pragma unroll
  for (int pass = 0; pass < 4; ++pass) {
    int c   = c0 + (t >> 4) + pass * 16;
    int pix = p0 + (t & 15) * 4;
    float ga = gamma[c] * rstd;
    float be = beta[c] - mean * ga;
    float4 v = *reinterpret_cast<const float4*>(&x[((size_t)(b*CCH + c)) * NPIX + pix]);
    int pl = (t & 15) * 4, cl = (t >> 4) + pass * 16;
    lt[pl+0][cl] = v.x*ga + be;
    lt[pl+1][cl] = v.y*ga + be;
    lt[pl+2][cl] = v.z*ga + be;
    lt[pl+3][cl] = v.w*ga + be;
  }
  __syncthreads();
  const int pl = t >> 2, cq = (t & 3) * 16;
  u32 wbuf[8];
  #pragma unroll
  for (int e = 0; e < 8; ++e) {
    u16 lo = f2bf(lt[pl][cq + e*2]);
    u16 hi = f2bf(lt[pl][cq + e*2 + 1]);
    wbuf[e] = (u32)lo | ((u32)hi << 16);
  }
  u32* dst = (u32*)&xnT[((size_t)(b*NPIX + p0 + pl)) * CCH + c0 + cq];
  #pragma unroll
  for (int e = 0; e < 8; ++e) dst[e] = wbuf[e];
}

// ---------------- fp32 -> bf16 weights, merged, Q rows pre-scaled ----------------
__global__ void f2bf_all(const float* __restrict__ wqkv, const float* __restrict__ wproj,
                         u16* __restrict__ wq, u16* __restrict__ wp, float qs) {
  int i = blockIdx.x * 256 + threadIdx.x;
  float4 v; u16* dst; float sc = 1.f;
  if (i < 196608) {
    v = reinterpret_cast<const float4*>(wqkv)[i];
    if (i < 65536) sc = qs;
    dst = wq + (size_t)i * 4;
  } else {
    v = reinterpret_cast<const float4*>(wproj)[i - 196608];
    dst = wp + (size_t)(i - 196608) * 4;
  }
  u32 lo = (u32)f2bf(v.x*sc) | ((u32)f2bf(v.y*sc) << 16);
  u32 hi = (u32)f2bf(v.z*sc) | ((u32)f2bf(v.w*sc) << 16);
  *reinterpret_cast<uint2*>(dst) = make_uint2(lo, hi);
}

// ---------------- merged QKV GEMM: 32x32 MFMA, dbuf-pipelined staging ----------------
__global__ __launch_bounds__(256, 2) void gemm_qkv(const u16* __restrict__ xnT,
                                                   const u16* __restrict__ wq_bf,
                                                   u16* __restrict__ outQ,
                                                   u16* __restrict__ outK,
                                                   u16* __restrict__ outV) {
  __shared__ __align__(16) char smem[65536];

  const int id = blockIdx.x;
  const int wg = (id & 7) * 192 + (id >> 3);
  const bool mode0 = (wg < 1024);
  int rt, ct;
  if (mode0) { rt = wg >> 3; ct = wg & 7; }
  else       { int w1 = wg - 1024; rt = w1 & 3; ct = w1 >> 2; }

  const char* Ab = mode0 ? (const char*)xnT + (size_t)rt * 131072
                         : (const char*)wq_bf + (size_t)(8 + rt) * 131072;
  const char* Bb = mode0 ? (const char*)wq_bf + (size_t)ct * 131072
                         : (const char*)xnT + (size_t)ct * 131072;

  const int t = threadIdx.x;
  const int lane = t & 63, w = t >> 6;
  const int q = lane & 31, hi = lane >> 5;
  const int rh = (w >> 1) * 64, ch = (w & 1) * 64;

  int soff[4];
  #pragma unroll
  for (int i = 0; i < 4; ++i) {
    int p = w*4096 + i*1024 + lane*16;
    int lrow = p >> 9, off = p & 511;
    int loff = off ^ ((lrow & 15) << 4);
    soff[i] = (lrow*4 + (loff >> 7)) * 1024 + (loff & 127);
  }

  #pragma unroll
  for (int i = 0; i < 4; ++i) {
    gload16(Ab + soff[i], smem +         w*4096 + i*1024);
    gload16(Bb + soff[i], smem + 16384 + w*4096 + i*1024);
  }

  f32x16 acc[2][2] = {};

  for (int kt = 0; kt < 8; ++kt) {
    asm volatile("s_waitcnt vmcnt(0)" ::: "memory");
    __syncthreads();
    const char* cur = smem + (kt & 1) * 32768;
    if (kt + 1 < 8) {
      char* nxt = smem + ((kt + 1) & 1) * 32768;
      #pragma unroll
      for (int i = 0; i < 4; ++i) {
        gload16(Ab + (kt+1)*128 + soff[i], nxt +         w*4096 + i*1024);
        gload16(Bb + (kt+1)*128 + soff[i], nxt + 16384 + w*4096 + i*1024);
      }
    }
    __builtin_amdgcn_s_setprio(1);
    #pragma unroll
    for (int ck = 0; ck < 4; ++ck) {
      short8 af0 = rd512(cur,         rh + q,      ck, hi);
      short8 af1 = rd512(cur,         rh + 32 + q, ck, hi);
      short8 bf0 = rd512(cur + 16384, ch + q,      ck, hi);
      short8 bf1 = rd512(cur + 16384, ch + 32 + q, ck, hi);
      acc[0][0] = __builtin_amdgcn_mfma_f32_32x32x16_bf16(af0, bf0, acc[0][0], 0, 0, 0);
      acc[0][1] = __builtin_amdgcn_mfma_f32_32x32x16_bf16(af0, bf1, acc[0][1], 0, 0, 0);
      acc[1][0] = __builtin_amdgcn_mfma_f32_32x32x16_bf16(af1, bf0, acc[1][0], 0, 0, 0);
      acc[1][1] = __builtin_amdgcn_mfma_f32_32x32x16_bf16(af1, bf1, acc[1][1], 0, 0, 0);
    }
    __builtin_amdgcn_s_setprio(0);
  }

  __syncthreads();
  u16* Dt = (u16*)smem;   // [128][136]
  #pragma unroll
  for (int r = 0; r < 16; ++r) {
    int ar = (r & 3) + 8*(r >> 2) + 4*hi;
    Dt[(rh +      ar) * 136 + ch +      q] = f2bf(acc[0][0][r]);
    Dt[(rh +      ar) * 136 + ch + 32 + q] = f2bf(acc[0][1][r]);
    Dt[(rh + 32 + ar) * 136 + ch +      q] = f2bf(acc[1][0][r]);
    Dt[(rh + 32 + ar) * 136 + ch + 32 + q] = f2bf(acc[1][1][r]);
  }
  __syncthreads();

  const int rl = t >> 1, hoff = (t & 1) * 64;
  uint4 buf[8];
  const uint4* s4 = reinterpret_cast<const uint4*>(&Dt[rl*136 + hoff]);
  #pragma unroll
  for (int e = 0; e < 8; ++e) buf[e] = s4[e];

  u16* gdst;
  if (mode0) {
    const int tok0 = rt * 128;
    const int b = tok0 >> 10, pix0 = tok0 & 1023;
    const int h = ct & 3;
    u16* base = (ct >= 4) ? outK : outQ;
    gdst = base + ((size_t)((b*NHEAD + h)) * NPIX + pix0 + rl) * HDIM + hoff;
  } else {
    const int m0 = rt * 128, tok0 = ct * 128;
    const int b = tok0 >> 10, pix0 = tok0 & 1023;
    gdst = outV + ((size_t)(b*CCH + m0 + rl)) * NPIX + pix0 + hoff;
  }
  uint4* g4 = reinterpret_cast<uint4*>(gdst);
  #pragma unroll
  for (int e = 0; e < 8; ++e) g4[e] = buf[e];
}

// ---------------- proj GEMM: dbuf-pipelined, fused residual + bias -> fp32 out ----------------
__global__ __launch_bounds__(256, 2) void gemm_proj(const u16* __restrict__ wp_bf,
                                                    const u16* __restrict__ attnO,
                                                    const float* __restrict__ xres,
                                                    const float* __restrict__ bias,
                                                    float* __restrict__ outF) {
  __shared__ __align__(16) char smem[65536];

  const int id = blockIdx.x;
  const int wg = (id & 7) * 64 + (id >> 3);
  const int rt = wg & 3, ct = wg >> 2;

  const char* Ab = (const char*)wp_bf + (size_t)rt * 131072;
  const char* Bb = (const char*)attnO + (size_t)ct * 131072;

  const int t = threadIdx.x;
  const int lane = t & 63, w = t >> 6;
  const int q = lane & 31, hi = lane >> 5;
  const int rh = (w >> 1) * 64, ch = (w & 1) * 64;

  int soff[4];
  #pragma unroll
  for (int i = 0; i < 4; ++i) {
    int p = w*4096 + i*1024 + lane*16;
    int lrow = p >> 9, off = p & 511;
    int loff = off ^ ((lrow & 15) << 4);
    soff[i] = (lrow*4 + (loff >> 7)) * 1024 + (loff & 127);
  }

  #pragma unroll
  for (int i = 0; i < 4; ++i) {
    gload16(Ab + soff[i], smem +         w*4096 + i*1024);
    gload16(Bb + soff[i], smem + 16384 + w*4096 + i*1024);
  }

  f32x16 acc[2][2] = {};

  for (int kt = 0; kt < 8; ++kt) {
    asm volatile("s_waitcnt vmcnt(0)" ::: "memory");
    __syncthreads();
    const char* cur = smem + (kt & 1) * 32768;
    if (kt + 1 < 8) {
      char* nxt = smem + ((kt + 1) & 1) * 32768;
      #pragma unroll
      for (int i = 0; i < 4; ++i) {
        gload16(Ab + (kt+1)*128 + soff[i], nxt +         w*4096 + i*1024);
        gload16(Bb + (kt+1)*128 + soff[i], nxt + 16384 + w*4096 + i*1024);
      }
    }
    __builtin_amdgcn_s_setprio(1);
    #pragma unroll
    for (int ck = 0; ck < 4; ++ck) {
      short8 af0 = rd512(cur,         rh + q,      ck, hi);
      short8 af1 = rd512(cur,         rh + 32 + q, ck, hi);
      short8 bf0 = rd512(cur + 16384, ch + q,      ck, hi);
      short8 bf1 = rd512(cur + 16384, ch + 32 + q, ck, hi);
      acc[0][0] = __builtin_amdgcn_mfma_f32_32x32x16_bf16(af0, bf0, acc[0][0], 0, 0, 0);
      acc[0][1] = __builtin_amdgcn_mfma_f32_32x32x16_bf16(af0, bf1, acc[0][1], 0, 0, 0);
      acc[1][0] = __builtin_amdgcn_mfma_f32_32x32x16_bf16(af1, bf0, acc[1][0], 0, 0, 0);
      acc[1][1] = __builtin_amdgcn_mfma_f32_32x32x16_bf16(af1, bf1, acc[1][1], 0, 0, 0);
    }
    __builtin_amdgcn_s_setprio(0);
  }

  const int m0 = rt * 128, tok0 = ct * 128;
  const int b = tok0 >> 10, pix0 = tok0 & 1023;
  #pragma unroll
  for (int r = 0; r < 16; ++r) {
    int ar = (r & 3) + 8*(r >> 2) + 4*hi;
    int m0r = m0 + rh + ar, m1r = m0 + rh + 32 + ar;
    size_t o00 = ((size_t)(b*CCH + m0r)) * NPIX + pix0 + ch + q;
    size_t o01 = o00 + 32;
    size_t o10 = ((size_t)(b*CCH + m1r)) * NPIX + pix0 + ch + q;
    size_t o11 = o10 + 32;
    outF[o00] = xres[o00] + acc[0][0][r] + bias[m0r];
    outF[o01] = xres[o01] + acc[0][1][r] + bias[m0r];
    outF[o10] = xres[o10] + acc[1][0][r] + bias[m1r];
    outF[o11] = xres[o11] + acc[1][1][r] + bias[m1r];
  }
}

// ---------------- Flash attention: kv-split x2, KVBLK=32, 4 blocks/CU ----------------
// Qt,Kt token-major [bh][pix][128]; Vb channel-major [b*512+m][1024].
// Writes unnormalized partial O (bf16) + partial l (f32); fixed-shift softmax -> exactly summable.
__global__ __launch_bounds__(256, 4) void attn_k(const u16* __restrict__ Qt,
                                                 const u16* __restrict__ Kt,
                                                 const u16* __restrict__ Vb,
                                                 u16* __restrict__ Opart,
                                                 float* __restrict__ lpart) {
  int id = blockIdx.x;
  int swz = (id & 7) * 128 + (id >> 3);   // 1024 blocks, 8 XCDs
  const int half = swz & 1;
  const int qt   = (swz >> 1) & 7;
  const int h    = (swz >> 4) & 3;
  const int b    = swz >> 6;
  const int bh   = b * NHEAD + h;

  __shared__ __align__(16) char smem[32768];  // K dbuf 2x8K @0 | V dbuf 2x8K @16384

  const int t = threadIdx.x;
  const int lane = t & 63, w = t >> 6;
  const int q = lane & 31, hi = lane >> 5;

  const u16*  Qb    = Qt + ((size_t)bh * NPIX + qt*128 + w*32 + q) * HDIM;
  const char* Kbase = (const char*)(Kt + (size_t)bh * NPIX * HDIM) + half * (512*256);
  const char* Vbase = (const char*)(Vb + ((size_t)b*CCH + h*HDIM) * NPIX) + half * 1024;

  short8 qf[8];
  #pragma unroll
  for (int ck = 0; ck < 8; ++ck)
    qf[ck] = *reinterpret_cast<const short8*>(&Qb[ck*16 + hi*8]);

  // staging source offsets (pre-swizzled 4-bit XOR, linear LDS dest), 2 chunks/thread
  // K LDS: [32 kv][256B].  V LDS: [32 rows][256B], channel c -> row c&31, slot c>>5.
  int koff[2], voff[2];
  #pragma unroll
  for (int i = 0; i < 2; ++i) {
    int d = (i*256 + t) * 16;          // 0..8191
    int r = d >> 8, cb = d & 255;
    int col = cb ^ ((r & 15) << 4);
    koff[i] = r*256 + col;
    int c = (col >> 6)*32 + r;
    voff[i] = c*2048 + (col & 63);
  }
  const int ldst0 = w*1024;            // wave-uniform LDS dest for chunk i: +i*4096

  const int ksw = (q & 15) << 4;

  f32x16 of[4] = {};
  float lsum = 0.f;
  short8 pf[2];

  // prologue: K(0)->kb0, V(0)->vb0, K(1)->kb1
  #pragma unroll
  for (int i = 0; i < 2; ++i) {
    gload16(Kbase + koff[i],            smem +          i*4096 + ldst0);
    gload16(Vbase + voff[i],            smem + 16384 +  i*4096 + ldst0);
    gload16(Kbase + 32*256 + koff[i],   smem +  8192 +  i*4096 + ldst0);
  }
  asm volatile("s_waitcnt vmcnt(0)" ::: "memory");
  __syncthreads();

  {
    f32x16 sn = {};
    #pragma unroll
    for (int ck = 0; ck < 8; ++ck) {
      const short8 kf = *reinterpret_cast<const short8*>(smem + q*256 + ((ck*32 + hi*16) ^ ksw));
      sn = __builtin_amdgcn_mfma_f32_32x32x16_bf16(kf, qf[ck], sn, 0, 0, 0);
    }
    lsum += softmax_pack32(sn, pf);
  }

  // main loop over 16 tiles of 32 kv
  for (int tt = 0; tt < 16; ++tt) {
    asm volatile("s_waitcnt vmcnt(0)" ::: "memory");
    __syncthreads();   // V(tt), K(tt+1) staged; all prior-cluster LDS reads done

    const char* kcur = smem + (((tt+1) & 1) << 13);
    const char* vcur = smem + 16384 + ((tt & 1) << 13);

    if (tt + 1 < 16) {
      char* vdst = smem + 16384 + (((tt+1) & 1) << 13);
      #pragma unroll
      for (int i = 0; i < 2; ++i)
        gload16(Vbase + (size_t)(tt+1)*64 + voff[i], vdst + i*4096 + ldst0);
    }
    if (tt + 2 < 16) {
      char* kdst = smem + ((tt & 1) << 13);
      #pragma unroll
      for (int i = 0; i < 2; ++i)
        gload16(Kbase + (size_t)(tt+2)*32*256 + koff[i], kdst + i*4096 + ldst0);
    }

    f32x16 sn = {};
    __builtin_amdgcn_s_setprio(1);
    if (tt + 1 < 16) {
      #pragma unroll
      for (int ck = 0; ck < 8; ++ck) {
        const short8 kf = *reinterpret_cast<const short8*>(kcur + q*256 + ((ck*32 + hi*16) ^ ksw));
        sn = __builtin_amdgcn_mfma_f32_32x32x16_bf16(kf, qf[ck], sn, 0, 0, 0);
      }
    }
    // PV(tt)
    #pragma unroll
    for (int cg = 0; cg < 4; ++cg) {
      #pragma unroll
      for (int kc = 0; kc < 2; ++kc)
        of[cg] = __builtin_amdgcn_mfma_f32_32x32x16_bf16(
            *reinterpret_cast<const short8*>(vcur + q*256 + ((cg*64 + kc*32 + hi*16) ^ ksw)),
            pf[kc], of[cg], 0, 0, 0);
    }
    __builtin_amdgcn_s_setprio(0);

    if (tt + 1 < 16)
      lsum += softmax_pack32(sn, pf);
  }

  // epilogue: unnormalized partial store + l
  const int qrow = qt*128 + w*32 + q;
  u16* orow = Opart + ((size_t)(half*64 + bh) * NPIX + qrow) * HDIM;
  #pragma unroll
  for (int cg = 0; cg < 4; ++cg) {
    #pragma unroll
    for (int u = 0; u < 8; ++u) {
      int c = cg*32 + ((2*u) & 3) + 8*(u >> 1) + 4*hi;
      u32 pk = (u32)f2bf(of[cg][2*u]) | ((u32)f2bf(of[cg][2*u+1]) << 16);
      *reinterpret_cast<u32*>(&orow[c]) = pk;
    }
  }
  lsum += __shfl_xor(lsum, 32);
  if (lane < 32)
    lpart[(size_t)(half*64 + bh) * NPIX + qrow] = lsum;
}

// ---------------- combine partials: attnO[tok][512] = (O0+O1)/(l0+l1) ----------------
__global__ void attn_combine(const u16* __restrict__ Opart, const float* __restrict__ lpart,
                             u16* __restrict__ attnO) {
  int g = blockIdx.x * 256 + threadIdx.x;     // 1,048,576 threads
  int qi = g >> 4;                            // bh*1024 + q  (0..65535)
  int seg = (g & 15) * 8;                     // channel offset
  const uint4 a = *reinterpret_cast<const uint4*>(Opart + ((size_t)qi) * HDIM + seg);
  const uint4 c = *reinterpret_cast<const uint4*>(Opart + ((size_t)(qi + 65536)) * HDIM + seg);
  float inv = 1.f / (lpart[qi] + lpart[qi + 65536]);
  u32 aw[4] = {a.x, a.y, a.z, a.w};
  u32 cw[4] = {c.x, c.y, c.z, c.w};
  u32 ow[4];
  #pragma unroll
  for (int e = 0; e < 4; ++e) {
    float lo = (bf2f_lo(aw[e]) + bf2f_lo(cw[e])) * inv;
    float hi = (bf2f_hi(aw[e]) + bf2f_hi(cw[e])) * inv;
    ow[e] = (u32)f2bf(lo) | ((u32)f2bf(hi) << 16);
  }
  int bh = qi >> 10, qq = qi & 1023;
  int bb = bh >> 2, hh = bh & 3;
  u16* dst = attnO + ((size_t)(bb * NPIX + qq)) * CCH + hh * HDIM + seg;
  *reinterpret_cast<uint4*>(dst) = make_uint4(ow[0], ow[1], ow[2], ow[3]);
}

// ---------------- launch ----------------
extern "C" void kernel_launch(void* const* d_in, const int* in_sizes, int n_in,
                              void* d_out, int out_size, void* d_ws, size_t ws_size,
                              hipStream_t stream) {
  const float* x     = (const float*)d_in[0];
  const float* gamma = (const float*)d_in[1];
  const float* beta  = (const float*)d_in[2];
  const float* wqkv  = (const float*)d_in[3];
  const float* wproj = (const float*)d_in[4];
  const float* bproj = (const float*)d_in[5];
  float* out = (float*)d_out;

  char* ws = (char*)d_ws;
  float* part   = (float*)ws;                          // 8 KB
  u16*   xnT    = (u16*)(ws + 8192);                   // 16 MB [16384][512]  (reused as Opart half 0)
  u16*   wq_bf  = (u16*)(ws + 8192 + (16u<<20));       // 1.5 MB
  u16*   wp_bf  = (u16*)((char*)wq_bf + 1572864);      // 0.5 MB
  u16*   Qt     = (u16*)((char*)wp_bf + 524288);       // 16 MB [bh][1024][128]
  u16*   Kt     = (u16*)((char*)Qt + (16u<<20));       // 16 MB
  u16*   Vb     = (u16*)((char*)Kt + (16u<<20));       // 16 MB [b*512+m][1024]
  u16*   attnO  = (u16*)((char*)Vb + (16u<<20));       // 16 MB [16384][512]
  u16*   Opart1 = (u16*)((char*)attnO + (16u<<20));    // 16 MB (half 1)
  float* lpart  = (float*)((char*)Opart1 + (16u<<20)); // 512 KB
  u16*   Opart  = xnT;                                 // half 0 overlays dead xnT

  const float qs = 0.08838834764831845f * 1.44269504088896f;
  (void)Opart1;  // Opart layout: [half][bh][1024][128] -> half1 must follow half0 contiguously?
  // NOTE: Opart indexing uses (half*64+bh) -> half1 lands at Opart + 64*1024*128 = xnT + 8M elems
  // = exactly the 16MB xnT region end. Place half 1 in Qt?? Qt is still live during attn.
  // -> Use a dedicated contiguous 32MB region instead: Opart = attnO region is too small.
  // Simplest safe layout: Opart spans attnO..Opart1 (32MB contiguous), attnO moves after lpart.
  u16* OpartBase = attnO;                               // 32 MB contiguous (attnO + Opart1 slots)
  u16* attnO2    = (u16*)((char*)lpart + 524288);       // 16 MB, final combined buffer

  gn_stats_k<<<dim3(1024), dim3(256), 0, stream>>>(x, part);
  gn_apply_t<<<dim3(16, 8, BATCH), dim3(256), 0, stream>>>(x, gamma, beta, part, xnT);
  f2bf_all<<<dim3(1024), dim3(256), 0, stream>>>(wqkv, wproj, wq_bf, wp_bf, qs);

  gemm_qkv<<<dim3(1536), dim3(256), 0, stream>>>(xnT, wq_bf, Qt, Kt, Vb);

  attn_k<<<dim3(1024), dim3(256), 0, stream>>>(Qt, Kt, Vb, OpartBase, lpart);

  attn_combine<<<dim3(4096), dim3(256), 0, stream>>>(OpartBase, lpart, attnO2);

  gemm_proj<<<dim3(512), dim3(256), 0, stream>>>(wp_bf, attnO2, x, bproj, out);
}

// Round 10
// 122.515 us; speedup vs baseline: 1.2021x; 1.2021x over previous
//
#include <hip/hip_runtime.h>
#include <stdint.h>

typedef unsigned short u16;
typedef unsigned int u32;
typedef __attribute__((ext_vector_type(8))) short short8;
typedef __attribute__((ext_vector_type(4))) float f32x4;
typedef __attribute__((ext_vector_type(16))) float f32x16;
typedef __attribute__((ext_vector_type(4))) u32 u32x4;

#define BATCH 16
#define CCH   512
#define NPIX  1024
#define NGRP  8
#define CPG   64
#define NHEAD 4
#define HDIM  128

__device__ __forceinline__ u16 f2bf(float f) {
  union { float f; u32 u; } v; v.f = f;
  u32 u = v.u;
  u32 r = (u + 0x7FFFu + ((u >> 16) & 1u)) >> 16;
  return (u16)r;
}

// async global->LDS, 16B per lane; dest = wave-uniform base + lane*16
__device__ __forceinline__ void gload16(const void* g, void* l) {
  typedef __attribute__((address_space(3))) u32 L;
  typedef __attribute__((address_space(1))) const u32 G;
  __builtin_amdgcn_global_load_lds((G*)(uintptr_t)g, (L*)(u32)(uintptr_t)l, 16, 0, 0);
}

#define CVTPK(dst, a, b) asm("v_cvt_pk_bf16_f32 %0, %1, %2" : "=v"(dst) : "v"(a), "v"(b))
#define PLSWAP(a, b) asm("v_permlane32_swap_b32 %0, %1" : "+v"(a), "+v"(b))

// 512B-pitch swizzled LDS fragment read (rows packed 4-per-512B, 4-bit XOR)
__device__ __forceinline__ short8 rd512(const char* base, int r, int ck, int hi) {
  int byte = ((r >> 2) * 512) +
             ((((r & 3) * 128) + ck * 32 + hi * 16) ^ (((r >> 2) & 15) << 4));
  return *reinterpret_cast<const short8*>(base + byte);
}

// softmax pack: s0/s1 (32 scores, log2-domain, fixed-shift) -> 4 P-fragments + wave psum
__device__ __forceinline__ float softmax_pack(const f32x16& s0, const f32x16& s1, short8* pf) {
  float ps[4] = {0.f, 0.f, 0.f, 0.f};
  u32 pw[16];
  #pragma unroll
  for (int u = 0; u < 8; ++u) {
    float pa = exp2f(s0[2*u]);  float pb = exp2f(s0[2*u+1]);
    float pc = exp2f(s1[2*u]);  float pd = exp2f(s1[2*u+1]);
    ps[u & 3] += (pa + pb) + (pc + pd);
    CVTPK(pw[u],     pa, pb);
    CVTPK(pw[8 + u], pc, pd);
  }
  PLSWAP(pw[0], pw[2]);  PLSWAP(pw[1], pw[3]);
  PLSWAP(pw[4], pw[6]);  PLSWAP(pw[5], pw[7]);
  PLSWAP(pw[8], pw[10]); PLSWAP(pw[9], pw[11]);
  PLSWAP(pw[12], pw[14]); PLSWAP(pw[13], pw[15]);
  #pragma unroll
  for (int f = 0; f < 4; ++f) {
    u32x4 t = {pw[f*4], pw[f*4+1], pw[f*4+2], pw[f*4+3]};
    pf[f] = __builtin_bit_cast(short8, t);
  }
  float psum = (ps[0] + ps[1]) + (ps[2] + ps[3]);
  psum += __shfl_xor(psum, 32);
  return psum;
}

// ---------------- GroupNorm partial stats ----------------
__global__ void gn_stats_k(const float* __restrict__ x, float* __restrict__ part) {
  int bg = blockIdx.x >> 3, sl = blockIdx.x & 7;
  const float* p = x + (size_t)bg * (CPG * NPIX) + sl * 8192;
  float s = 0.f, ss = 0.f;
  for (int i = threadIdx.x; i < 2048; i += 256) {
    float4 v = reinterpret_cast<const float4*>(p)[i];
    s  += v.x + v.y + v.z + v.w;
    ss += v.x*v.x + v.y*v.y + v.z*v.z + v.w*v.w;
  }
  for (int o = 32; o > 0; o >>= 1) { s += __shfl_down(s, o); ss += __shfl_down(ss, o); }
  __shared__ float sh[8];
  int wid = threadIdx.x >> 6;
  if ((threadIdx.x & 63) == 0) { sh[wid*2] = s; sh[wid*2+1] = ss; }
  __syncthreads();
  if (threadIdx.x == 0) {
    part[blockIdx.x*2]   = sh[0]+sh[2]+sh[4]+sh[6];
    part[blockIdx.x*2+1] = sh[1]+sh[3]+sh[5]+sh[7];
  }
}

// ---------------- GroupNorm apply + transpose -> token-major bf16 xnT[tok][512] ----------------
__global__ __launch_bounds__(256) void gn_apply_t(const float* __restrict__ x,
                                                  const float* __restrict__ gamma,
                                                  const float* __restrict__ beta,
                                                  const float* __restrict__ part,
                                                  u16* __restrict__ xnT) {
  const int p0 = blockIdx.x * 64;
  const int c0 = blockIdx.y * 64;
  const int b  = blockIdx.z;
  __shared__ float lt[64][66];

  const int bg = b * NGRP + (c0 >> 6);
  float s = 0.f, ss = 0.f;
  #pragma unroll
  for (int k2 = 0; k2 < 8; ++k2) { s += part[(bg*8 + k2)*2]; ss += part[(bg*8 + k2)*2 + 1]; }
  const float invn = 1.f / (float)(CPG * NPIX);
  const float mean = s * invn;
  const float rstd = rsqrtf(ss * invn - mean * mean + 1e-5f);

  const int t = threadIdx.x;
  #pragma unroll
  for (int pass = 0; pass < 4; ++pass) {
    int c   = c0 + (t >> 4) + pass * 16;
    int pix = p0 + (t & 15) * 4;
    float ga = gamma[c] * rstd;
    float be = beta[c] - mean * ga;
    float4 v = *reinterpret_cast<const float4*>(&x[((size_t)(b*CCH + c)) * NPIX + pix]);
    int pl = (t & 15) * 4, cl = (t >> 4) + pass * 16;
    lt[pl+0][cl] = v.x*ga + be;
    lt[pl+1][cl] = v.y*ga + be;
    lt[pl+2][cl] = v.z*ga + be;
    lt[pl+3][cl] = v.w*ga + be;
  }
  __syncthreads();
  const int pl = t >> 2, cq = (t & 3) * 16;
  u32 wbuf[8];
  #pragma unroll
  for (int e = 0; e < 8; ++e) {
    u16 lo = f2bf(lt[pl][cq + e*2]);
    u16 hi = f2bf(lt[pl][cq + e*2 + 1]);
    wbuf[e] = (u32)lo | ((u32)hi << 16);
  }
  u32* dst = (u32*)&xnT[((size_t)(b*NPIX + p0 + pl)) * CCH + c0 + cq];
  #pragma unroll
  for (int e = 0; e < 8; ++e) dst[e] = wbuf[e];
}

// ---------------- fp32 -> bf16 weights, merged, Q rows pre-scaled ----------------
__global__ void f2bf_all(const float* __restrict__ wqkv, const float* __restrict__ wproj,
                         u16* __restrict__ wq, u16* __restrict__ wp, float qs) {
  int i = blockIdx.x * 256 + threadIdx.x;
  float4 v; u16* dst; float sc = 1.f;
  if (i < 196608) {
    v = reinterpret_cast<const float4*>(wqkv)[i];
    if (i < 65536) sc = qs;
    dst = wq + (size_t)i * 4;
  } else {
    v = reinterpret_cast<const float4*>(wproj)[i - 196608];
    dst = wp + (size_t)(i - 196608) * 4;
  }
  u32 lo = (u32)f2bf(v.x*sc) | ((u32)f2bf(v.y*sc) << 16);
  u32 hi = (u32)f2bf(v.z*sc) | ((u32)f2bf(v.w*sc) << 16);
  *reinterpret_cast<uint2*>(dst) = make_uint2(lo, hi);
}

// ---------------- merged QKV GEMM: 32x32 MFMA, dbuf-pipelined staging ----------------
__global__ __launch_bounds__(256, 2) void gemm_qkv(const u16* __restrict__ xnT,
                                                   const u16* __restrict__ wq_bf,
                                                   u16* __restrict__ outQ,
                                                   u16* __restrict__ outK,
                                                   u16* __restrict__ outV) {
  __shared__ __align__(16) char smem[65536];

  const int id = blockIdx.x;
  const int wg = (id & 7) * 192 + (id >> 3);
  const bool mode0 = (wg < 1024);
  int rt, ct;
  if (mode0) { rt = wg >> 3; ct = wg & 7; }
  else       { int w1 = wg - 1024; rt = w1 & 3; ct = w1 >> 2; }

  const char* Ab = mode0 ? (const char*)xnT + (size_t)rt * 131072
                         : (const char*)wq_bf + (size_t)(8 + rt) * 131072;
  const char* Bb = mode0 ? (const char*)wq_bf + (size_t)ct * 131072
                         : (const char*)xnT + (size_t)ct * 131072;

  const int t = threadIdx.x;
  const int lane = t & 63, w = t >> 6;
  const int q = lane & 31, hi = lane >> 5;
  const int rh = (w >> 1) * 64, ch = (w & 1) * 64;

  int soff[4];
  #pragma unroll
  for (int i = 0; i < 4; ++i) {
    int p = w*4096 + i*1024 + lane*16;
    int lrow = p >> 9, off = p & 511;
    int loff = off ^ ((lrow & 15) << 4);
    soff[i] = (lrow*4 + (loff >> 7)) * 1024 + (loff & 127);
  }

  #pragma unroll
  for (int i = 0; i < 4; ++i) {
    gload16(Ab + soff[i], smem +         w*4096 + i*1024);
    gload16(Bb + soff[i], smem + 16384 + w*4096 + i*1024);
  }

  f32x16 acc[2][2] = {};

  for (int kt = 0; kt < 8; ++kt) {
    asm volatile("s_waitcnt vmcnt(0)" ::: "memory");
    __syncthreads();
    const char* cur = smem + (kt & 1) * 32768;
    if (kt + 1 < 8) {
      char* nxt = smem + ((kt + 1) & 1) * 32768;
      #pragma unroll
      for (int i = 0; i < 4; ++i) {
        gload16(Ab + (kt+1)*128 + soff[i], nxt +         w*4096 + i*1024);
        gload16(Bb + (kt+1)*128 + soff[i], nxt + 16384 + w*4096 + i*1024);
      }
    }
    __builtin_amdgcn_s_setprio(1);
    #pragma unroll
    for (int ck = 0; ck < 4; ++ck) {
      short8 af0 = rd512(cur,         rh + q,      ck, hi);
      short8 af1 = rd512(cur,         rh + 32 + q, ck, hi);
      short8 bf0 = rd512(cur + 16384, ch + q,      ck, hi);
      short8 bf1 = rd512(cur + 16384, ch + 32 + q, ck, hi);
      acc[0][0] = __builtin_amdgcn_mfma_f32_32x32x16_bf16(af0, bf0, acc[0][0], 0, 0, 0);
      acc[0][1] = __builtin_amdgcn_mfma_f32_32x32x16_bf16(af0, bf1, acc[0][1], 0, 0, 0);
      acc[1][0] = __builtin_amdgcn_mfma_f32_32x32x16_bf16(af1, bf0, acc[1][0], 0, 0, 0);
      acc[1][1] = __builtin_amdgcn_mfma_f32_32x32x16_bf16(af1, bf1, acc[1][1], 0, 0, 0);
    }
    __builtin_amdgcn_s_setprio(0);
  }

  __syncthreads();
  u16* Dt = (u16*)smem;   // [128][136]
  #pragma unroll
  for (int r = 0; r < 16; ++r) {
    int ar = (r & 3) + 8*(r >> 2) + 4*hi;
    Dt[(rh +      ar) * 136 + ch +      q] = f2bf(acc[0][0][r]);
    Dt[(rh +      ar) * 136 + ch + 32 + q] = f2bf(acc[0][1][r]);
    Dt[(rh + 32 + ar) * 136 + ch +      q] = f2bf(acc[1][0][r]);
    Dt[(rh + 32 + ar) * 136 + ch + 32 + q] = f2bf(acc[1][1][r]);
  }
  __syncthreads();

  const int rl = t >> 1, hoff = (t & 1) * 64;
  uint4 buf[8];
  const uint4* s4 = reinterpret_cast<const uint4*>(&Dt[rl*136 + hoff]);
  #pragma unroll
  for (int e = 0; e < 8; ++e) buf[e] = s4[e];

  u16* gdst;
  if (mode0) {
    const int tok0 = rt * 128;
    const int b = tok0 >> 10, pix0 = tok0 & 1023;
    const int h = ct & 3;
    u16* base = (ct >= 4) ? outK : outQ;
    gdst = base + ((size_t)((b*NHEAD + h)) * NPIX + pix0 + rl) * HDIM + hoff;
  } else {
    const int m0 = rt * 128, tok0 = ct * 128;
    const int b = tok0 >> 10, pix0 = tok0 & 1023;
    gdst = outV + ((size_t)(b*CCH + m0 + rl)) * NPIX + pix0 + hoff;
  }
  uint4* g4 = reinterpret_cast<uint4*>(gdst);
  #pragma unroll
  for (int e = 0; e < 8; ++e) g4[e] = buf[e];
}

// ---------------- proj GEMM: dbuf-pipelined, fused residual + bias -> fp32 out ----------------
__global__ __launch_bounds__(256, 2) void gemm_proj(const u16* __restrict__ wp_bf,
                                                    const u16* __restrict__ attnO,
                                                    const float* __restrict__ xres,
                                                    const float* __restrict__ bias,
                                                    float* __restrict__ outF) {
  __shared__ __align__(16) char smem[65536];

  const int id = blockIdx.x;
  const int wg = (id & 7) * 64 + (id >> 3);
  const int rt = wg & 3, ct = wg >> 2;

  const char* Ab = (const char*)wp_bf + (size_t)rt * 131072;
  const char* Bb = (const char*)attnO + (size_t)ct * 131072;

  const int t = threadIdx.x;
  const int lane = t & 63, w = t >> 6;
  const int q = lane & 31, hi = lane >> 5;
  const int rh = (w >> 1) * 64, ch = (w & 1) * 64;

  int soff[4];
  #pragma unroll
  for (int i = 0; i < 4; ++i) {
    int p = w*4096 + i*1024 + lane*16;
    int lrow = p >> 9, off = p & 511;
    int loff = off ^ ((lrow & 15) << 4);
    soff[i] = (lrow*4 + (loff >> 7)) * 1024 + (loff & 127);
  }

  #pragma unroll
  for (int i = 0; i < 4; ++i) {
    gload16(Ab + soff[i], smem +         w*4096 + i*1024);
    gload16(Bb + soff[i], smem + 16384 + w*4096 + i*1024);
  }

  f32x16 acc[2][2] = {};

  for (int kt = 0; kt < 8; ++kt) {
    asm volatile("s_waitcnt vmcnt(0)" ::: "memory");
    __syncthreads();
    const char* cur = smem + (kt & 1) * 32768;
    if (kt + 1 < 8) {
      char* nxt = smem + ((kt + 1) & 1) * 32768;
      #pragma unroll
      for (int i = 0; i < 4; ++i) {
        gload16(Ab + (kt+1)*128 + soff[i], nxt +         w*4096 + i*1024);
        gload16(Bb + (kt+1)*128 + soff[i], nxt + 16384 + w*4096 + i*1024);
      }
    }
    __builtin_amdgcn_s_setprio(1);
    #pragma unroll
    for (int ck = 0; ck < 4; ++ck) {
      short8 af0 = rd512(cur,         rh + q,      ck, hi);
      short8 af1 = rd512(cur,         rh + 32 + q, ck, hi);
      short8 bf0 = rd512(cur + 16384, ch + q,      ck, hi);
      short8 bf1 = rd512(cur + 16384, ch + 32 + q, ck, hi);
      acc[0][0] = __builtin_amdgcn_mfma_f32_32x32x16_bf16(af0, bf0, acc[0][0], 0, 0, 0);
      acc[0][1] = __builtin_amdgcn_mfma_f32_32x32x16_bf16(af0, bf1, acc[0][1], 0, 0, 0);
      acc[1][0] = __builtin_amdgcn_mfma_f32_32x32x16_bf16(af1, bf0, acc[1][0], 0, 0, 0);
      acc[1][1] = __builtin_amdgcn_mfma_f32_32x32x16_bf16(af1, bf1, acc[1][1], 0, 0, 0);
    }
    __builtin_amdgcn_s_setprio(0);
  }

  const int m0 = rt * 128, tok0 = ct * 128;
  const int b = tok0 >> 10, pix0 = tok0 & 1023;
  #pragma unroll
  for (int r = 0; r < 16; ++r) {
    int ar = (r & 3) + 8*(r >> 2) + 4*hi;
    int m0r = m0 + rh + ar, m1r = m0 + rh + 32 + ar;
    size_t o00 = ((size_t)(b*CCH + m0r)) * NPIX + pix0 + ch + q;
    size_t o01 = o00 + 32;
    size_t o10 = ((size_t)(b*CCH + m1r)) * NPIX + pix0 + ch + q;
    size_t o11 = o10 + 32;
    outF[o00] = xres[o00] + acc[0][0][r] + bias[m0r];
    outF[o01] = xres[o01] + acc[0][1][r] + bias[m0r];
    outF[o10] = xres[o10] + acc[1][0][r] + bias[m1r];
    outF[o11] = xres[o11] + acc[1][1][r] + bias[m1r];
  }
}

// ---------------- Flash attention: R7 structure + T4 counted-vmcnt pipeline ----------------
// Issue discipline: K always issued BEFORE V in each iter, so at the top of the next iter
// the outstanding queue is [K(tt+1) x4 (older), V(tt) x4 (newer)]:
//   vmcnt(4)  -> K(tt+1) landed (leave V in flight)      ... before QK
//   vmcnt(8)  -> V(tt) landed (leave this iter's 8 new)  ... before PV
__global__ __launch_bounds__(256, 2) void attn_k(const u16* __restrict__ Qt,
                                                 const u16* __restrict__ Kt,
                                                 const u16* __restrict__ Vb,
                                                 u16* __restrict__ attnO) {
  int id = blockIdx.x;
  int swz = (id & 7) * 64 + (id >> 3);
  const int qt = swz & 7;
  const int h  = (swz >> 3) & 3;
  const int b  = swz >> 5;
  const int bh = b * NHEAD + h;

  __shared__ __align__(16) char smem[65536];  // K dbuf 2x16K @0 | V dbuf 2x16K @32768

  const int t = threadIdx.x;
  const int lane = t & 63, w = t >> 6;
  const int q = lane & 31, hi = lane >> 5;

  const u16*  Qb    = Qt + ((size_t)bh * NPIX + qt*128 + w*32 + q) * HDIM;
  const char* Kbase = (const char*)(Kt + (size_t)bh * NPIX * HDIM);
  const char* Vbase = (const char*)(Vb + ((size_t)b*CCH + h*HDIM) * NPIX);

  short8 qf[8];
  #pragma unroll
  for (int ck = 0; ck < 8; ++ck)
    qf[ck] = *reinterpret_cast<const short8*>(&Qb[ck*16 + hi*8]);

  int koff[4], voff[4];
  #pragma unroll
  for (int i = 0; i < 4; ++i) {
    int d = w*4096 + i*1024 + lane*16;
    int r = d >> 8, cb = d & 255;
    int col = cb ^ ((r & 15) << 4);
    koff[i] = r*256 + col;
    int half = col >> 7, kvb = col & 127;
    voff[i] = (2*r + half)*2048 + kvb;
  }

  const int ksw = (q & 15) << 4;
  const int vsw = (q >> 1) << 4;

  f32x16 of[4] = {};
  float l_run = 0.f;
  short8 pf[4];

  // prologue: issue K0->kb0, K1->kb1, V0->vb0 (K before V); full drain once
  #pragma unroll
  for (int i = 0; i < 4; ++i)
    gload16(Kbase + koff[i],                  smem +         w*4096 + i*1024);
  #pragma unroll
  for (int i = 0; i < 4; ++i)
    gload16(Kbase + (size_t)64*256 + koff[i], smem + 16384 + w*4096 + i*1024);
  #pragma unroll
  for (int i = 0; i < 4; ++i)
    gload16(Vbase + voff[i],                  smem + 32768 + w*4096 + i*1024);
  asm volatile("s_waitcnt vmcnt(0)" ::: "memory");
  __syncthreads();

  {
    f32x16 sn[2] = {};
    #pragma unroll
    for (int ck = 0; ck < 8; ++ck) {
      const short8 kf0 = *reinterpret_cast<const short8*>(smem + q*256      + ((ck*32 + hi*16) ^ ksw));
      const short8 kf1 = *reinterpret_cast<const short8*>(smem + (32+q)*256 + ((ck*32 + hi*16) ^ ksw));
      sn[0] = __builtin_amdgcn_mfma_f32_32x32x16_bf16(kf0, qf[ck], sn[0], 0, 0, 0);
      sn[1] = __builtin_amdgcn_mfma_f32_32x32x16_bf16(kf1, qf[ck], sn[1], 0, 0, 0);
    }
    l_run += softmax_pack(sn[0], sn[1], pf);
  }

  // main loop: iter tt = {QK_{tt+1} || PV_tt}, counted waits, raw barriers
  for (int tt = 0; tt < 16; ++tt) {
    asm volatile("s_waitcnt vmcnt(4)" ::: "memory");   // K(tt+1) landed (mine); V(tt) may fly
    __builtin_amdgcn_s_barrier();                      // all waves' K(tt+1) in LDS; prev reads done

    const char* kcur = smem + (((tt+1) & 1) << 14);
    const char* vcur = smem + 32768 + ((tt & 1) << 14);

    // issue K first (older), then V
    if (tt + 2 < 16) {
      char* kdst = smem + ((tt & 1) << 14);
      #pragma unroll
      for (int i = 0; i < 4; ++i)
        gload16(Kbase + (size_t)(tt+2)*64*256 + koff[i], kdst + w*4096 + i*1024);
    }
    if (tt + 1 < 16) {
      char* vdst = smem + 32768 + (((tt+1) & 1) << 14);
      #pragma unroll
      for (int i = 0; i < 4; ++i)
        gload16(Vbase + (size_t)(tt+1)*128 + voff[i], vdst + w*4096 + i*1024);
    }

    f32x16 sn[2] = {};
    __builtin_amdgcn_s_setprio(1);
    if (tt + 1 < 16) {
      #pragma unroll
      for (int ck = 0; ck < 8; ++ck) {
        const short8 kf0 = *reinterpret_cast<const short8*>(kcur + q*256      + ((ck*32 + hi*16) ^ ksw));
        const short8 kf1 = *reinterpret_cast<const short8*>(kcur + (32+q)*256 + ((ck*32 + hi*16) ^ ksw));
        sn[0] = __builtin_amdgcn_mfma_f32_32x32x16_bf16(kf0, qf[ck], sn[0], 0, 0, 0);
        sn[1] = __builtin_amdgcn_mfma_f32_32x32x16_bf16(kf1, qf[ck], sn[1], 0, 0, 0);
      }
    }
    __builtin_amdgcn_s_setprio(0);

    // V(tt) wait: leave this iter's fresh loads in flight
    if (tt < 14)       asm volatile("s_waitcnt vmcnt(8)" ::: "memory");
    else if (tt == 14) asm volatile("s_waitcnt vmcnt(4)" ::: "memory");
    else               asm volatile("s_waitcnt vmcnt(0)" ::: "memory");
    __builtin_amdgcn_s_barrier();                      // all waves' V(tt) in LDS

    __builtin_amdgcn_s_setprio(1);
    #pragma unroll
    for (int cg = 0; cg < 4; ++cg) {
      const char* vrow = vcur + (cg*16 + (q >> 1))*256;
      const int hb = (q & 1) << 7;
      #pragma unroll
      for (int kc = 0; kc < 4; ++kc)
        of[cg] = __builtin_amdgcn_mfma_f32_32x32x16_bf16(
            *reinterpret_cast<const short8*>(vrow + ((hb + kc*32 + hi*16) ^ vsw)),
            pf[kc], of[cg], 0, 0, 0);
    }
    __builtin_amdgcn_s_setprio(0);

    if (tt + 1 < 16)
      l_run += softmax_pack(sn[0], sn[1], pf);
  }

  // epilogue
  float inv = 1.f / l_run;
  u16* orow = attnO + ((size_t)(b*NPIX + qt*128 + w*32 + q)) * CCH + h*HDIM;
  #pragma unroll
  for (int cg = 0; cg < 4; ++cg) {
    #pragma unroll
    for (int u = 0; u < 8; ++u) {
      int c = cg*32 + ((2*u) & 3) + 8*(u >> 1) + 4*hi;
      u32 pk = (u32)f2bf(of[cg][2*u] * inv) | ((u32)f2bf(of[cg][2*u+1] * inv) << 16);
      *reinterpret_cast<u32*>(&orow[c]) = pk;
    }
  }
}

// ---------------- launch ----------------
extern "C" void kernel_launch(void* const* d_in, const int* in_sizes, int n_in,
                              void* d_out, int out_size, void* d_ws, size_t ws_size,
                              hipStream_t stream) {
  const float* x     = (const float*)d_in[0];
  const float* gamma = (const float*)d_in[1];
  const float* beta  = (const float*)d_in[2];
  const float* wqkv  = (const float*)d_in[3];
  const float* wproj = (const float*)d_in[4];
  const float* bproj = (const float*)d_in[5];
  float* out = (float*)d_out;

  char* ws = (char*)d_ws;
  float* part   = (float*)ws;                          // 8 KB
  u16*   xnT    = (u16*)(ws + 8192);                   // 16 MB [16384][512]
  u16*   wq_bf  = (u16*)(ws + 8192 + (16u<<20));       // 1.5 MB
  u16*   wp_bf  = (u16*)((char*)wq_bf + 1572864);      // 0.5 MB
  u16*   Qt     = (u16*)((char*)wp_bf + 524288);       // 16 MB [bh][1024][128]
  u16*   Kt     = (u16*)((char*)Qt + (16u<<20));       // 16 MB
  u16*   Vb     = (u16*)((char*)Kt + (16u<<20));       // 16 MB [b*512+m][1024]
  u16*   attnO  = (u16*)((char*)Vb + (16u<<20));       // 16 MB [16384][512]

  const float qs = 0.08838834764831845f * 1.44269504088896f;

  gn_stats_k<<<dim3(1024), dim3(256), 0, stream>>>(x, part);
  gn_apply_t<<<dim3(16, 8, BATCH), dim3(256), 0, stream>>>(x, gamma, beta, part, xnT);
  f2bf_all<<<dim3(1024), dim3(256), 0, stream>>>(wqkv, wproj, wq_bf, wp_bf, qs);

  gemm_qkv<<<dim3(1536), dim3(256), 0, stream>>>(xnT, wq_bf, Qt, Kt, Vb);

  attn_k<<<dim3(512), dim3(256), 0, stream>>>(Qt, Kt, Vb, attnO);

  gemm_proj<<<dim3(512), dim3(256), 0, stream>>>(wp_bf, attnO, x, bproj, out);
}